// Round 3
// baseline (776.444 us; speedup 1.0000x reference)
//
#include <hip/hip_runtime.h>

#define S_LEN 2048
#define DM    512
#define NH    8
#define HD    64

typedef unsigned short u16;
typedef unsigned int   u32;
typedef __bf16 bf16_t;
typedef bf16_t bf16x8 __attribute__((ext_vector_type(8)));
typedef float  f32x4  __attribute__((ext_vector_type(4)));

// round-to-nearest-even fp32 -> bf16
__device__ __forceinline__ u16 f2bf(float f) {
    u32 u = __float_as_uint(f);
    u += 0x7FFFu + ((u >> 16) & 1u);
    return (u16)(u >> 16);
}

// async global->LDS, 16B per lane; LDS dest = wave-uniform base + lane*16
__device__ __forceinline__ void g2l16(const u16* g, u16* l) {
    __builtin_amdgcn_global_load_lds(
        (const __attribute__((address_space(1))) u32*)g,
        (__attribute__((address_space(3))) u32*)l,
        16, 0, 0);
}

__device__ __forceinline__ float qmax16(float v) {
    v = fmaxf(v, __shfl_xor(v, 1));
    v = fmaxf(v, __shfl_xor(v, 2));
    v = fmaxf(v, __shfl_xor(v, 4));
    v = fmaxf(v, __shfl_xor(v, 8));
    return v;
}
__device__ __forceinline__ float qsum16(float v) {
    v += __shfl_xor(v, 1);
    v += __shfl_xor(v, 2);
    v += __shfl_xor(v, 4);
    v += __shfl_xor(v, 8);
    return v;
}

// ============================================================
// fp32 -> bf16 conversion pre-pass. y selects source.
// ============================================================
__global__ __launch_bounds__(256) void cvt_bf16(
    const float* __restrict__ x,
    const float* __restrict__ wq, const float* __restrict__ wk,
    const float* __restrict__ wv, const float* __restrict__ wo,
    u16* __restrict__ xb, u16* __restrict__ wqb, u16* __restrict__ wkb,
    u16* __restrict__ wvb, u16* __restrict__ wob)
{
    const int y = blockIdx.y;
    const float* src; u16* dst; int n;
    if (y == 0)      { src = x;  dst = xb;  n = 4 * S_LEN * DM; }
    else if (y == 1) { src = wq; dst = wqb; n = DM * DM; }
    else if (y == 2) { src = wk; dst = wkb; n = DM * DM; }
    else if (y == 3) { src = wv; dst = wvb; n = DM * DM; }
    else             { src = wo; dst = wob; n = DM * DM; }
    int idx = (blockIdx.x * 256 + threadIdx.x) * 8;
    if (idx >= n) return;
    float4 f0 = *(const float4*)(src + idx);
    float4 f1 = *(const float4*)(src + idx + 4);
    u32 p0 = (u32)f2bf(f0.x) | ((u32)f2bf(f0.y) << 16);
    u32 p1 = (u32)f2bf(f0.z) | ((u32)f2bf(f0.w) << 16);
    u32 p2 = (u32)f2bf(f1.x) | ((u32)f2bf(f1.y) << 16);
    u32 p3 = (u32)f2bf(f1.z) | ((u32)f2bf(f1.w) << 16);
    *(uint4*)(dst + idx) = make_uint4(p0, p1, p2, p3);
}

// ============================================================
// Fused QKV MFMA GEMM: C = X @ W^T + b, 128x128 tile, BK=32.
// m97-style: global_load_lds width-16 staging. XOR swizzle applied on the
// GLOBAL source side (lane reads kq^f(row)); LDS dest is lane-linear chunks
// chunk(row,kqs) = row*4 + kqs, so stored[row][kqs] = global[row][kqs^f(row)],
// f(row) = (row>>1)&3. Frag read: chunk = row*4 + (quad ^ f(row)) -> 2-way
// bank aliasing (free, m136). Output bf16 in [B,H,S,HD], bias fused.
// ============================================================
__global__ __launch_bounds__(256) void qkv_gemm(
    const u16* __restrict__ xb,
    const u16* __restrict__ Wqb, const u16* __restrict__ Wkb, const u16* __restrict__ Wvb,
    const float* __restrict__ bq, const float* __restrict__ bk, const float* __restrict__ bv,
    u16* __restrict__ Qb, u16* __restrict__ Kb, u16* __restrict__ Vb)
{
    __shared__ u16 Als[4096];   // 128 rows x 32 k, chunks of 8
    __shared__ u16 Bls[4096];

    const int t = threadIdx.x;
    const int lane = t & 63, w = t >> 6;
    const int ln = lane & 15, quad = lane >> 4;
    const int wm = w >> 1, wn = w & 1;
    const int m0 = blockIdx.x * 128;
    const int mat = blockIdx.y >> 2;          // 0=Q 1=K 2=V
    const int n0 = (blockIdx.y & 3) * 128;

    const u16* __restrict__ Wb     = (mat == 0) ? Wqb : (mat == 1) ? Wkb : Wvb;
    const float* __restrict__ bias = (mat == 0) ? bq : (mat == 1) ? bk : bv;
    u16* __restrict__ outp         = (mat == 0) ? Qb : (mat == 1) ? Kb : Vb;

    // staging: 2 instr/wave for A, 2 for B; chunk = (w*2+cc)*64 + lane
    const int ch0 = (w * 2 + 0) * 64 + lane;
    const int ch1 = (w * 2 + 1) * 64 + lane;
    const int sr0 = ch0 >> 2, sk0 = (ch0 & 3) ^ ((sr0 >> 1) & 3);
    const int sr1 = ch1 >> 2, sk1 = (ch1 & 3) ^ ((sr1 >> 1) & 3);
    const u16* pA0 = xb + (size_t)(m0 + sr0) * DM + sk0 * 8;
    const u16* pA1 = xb + (size_t)(m0 + sr1) * DM + sk1 * 8;
    const u16* pB0 = Wb + (size_t)(n0 + sr0) * DM + sk0 * 8;
    const u16* pB1 = Wb + (size_t)(n0 + sr1) * DM + sk1 * 8;
    u16* lds0 = (u16*)((w * 2 + 0) * 512);    // element offsets (chunk*8)
    u16* lds1 = (u16*)((w * 2 + 1) * 512);
    u16* lA0 = Als + (w * 2 + 0) * 512;
    u16* lA1 = Als + (w * 2 + 1) * 512;
    u16* lB0 = Bls + (w * 2 + 0) * 512;
    u16* lB1 = Bls + (w * 2 + 1) * 512;
    (void)lds0; (void)lds1;

    f32x4 acc[4][4] = {};
    for (int k0 = 0; k0 < DM; k0 += 32) {
        __syncthreads();
        g2l16(pA0 + k0, lA0);
        g2l16(pA1 + k0, lA1);
        g2l16(pB0 + k0, lB0);
        g2l16(pB1 + k0, lB1);
        __syncthreads();
        bf16x8 af[4], bf8[4];
        #pragma unroll
        for (int i = 0; i < 4; ++i) {
            int row = wm * 64 + i * 16 + ln;
            af[i] = *(const bf16x8*)(Als + (row * 4 + (quad ^ ((row >> 1) & 3))) * 8);
        }
        #pragma unroll
        for (int j = 0; j < 4; ++j) {
            int row = wn * 64 + j * 16 + ln;
            bf8[j] = *(const bf16x8*)(Bls + (row * 4 + (quad ^ ((row >> 1) & 3))) * 8);
        }
        #pragma unroll
        for (int i = 0; i < 4; ++i)
            #pragma unroll
            for (int j = 0; j < 4; ++j)
                acc[i][j] = __builtin_amdgcn_mfma_f32_16x16x32_bf16(af[i], bf8[j], acc[i][j], 0, 0, 0);
    }

    // epilogue: C/D layout col=lane&15, row=quad*4+reg  [m89/m91]
    #pragma unroll
    for (int j = 0; j < 4; ++j) {
        int colg = n0 + wn * 64 + j * 16 + ln;
        float bj = bias[colg];
        int h = colg >> 6, d = colg & 63;
        #pragma unroll
        for (int i = 0; i < 4; ++i) {
            int mbase = m0 + wm * 64 + i * 16 + quad * 4;
            #pragma unroll
            for (int r = 0; r < 4; ++r) {
                int m = mbase + r;
                int bb = m >> 11, s = m & 2047;
                outp[(((size_t)bb * NH + h) * S_LEN + s) * HD + d] = f2bf(acc[i][j][r] + bj);
            }
        }
    }
}

// ============================================================
// Flash attention, bf16 MFMA, causal. grid = (32, B*H).
// Block: 64 q-rows, 4 waves x 16 rows. K/V tiles of 64 keys.
// qt swizzled (x+y)&31 for load balance. Softmax in registers,
// exp2-domain (log2e folded into scale). Ps is wave-private.
// 16 KB LDS -> ~4 blocks/CU co-resident.
// ============================================================
__global__ __launch_bounds__(256) void attn_mfma(
    const u16* __restrict__ Qb, const u16* __restrict__ Kb, const u16* __restrict__ Vb,
    u16* __restrict__ Attb)
{
    __shared__ u16 Qls[4096];   // 64 q x 64 d
    __shared__ u16 Kls[4096];   // 64 k x 64 d
    __shared__ u16 Vt[4096];    // 64 d x 64 k (transposed)
    __shared__ u16 Ps[4096];    // 64 q x 64 k, wave-private 16-row slabs

    const int t = threadIdx.x;
    const int lane = t & 63, w = t >> 6;
    const int ln = lane & 15, quad = lane >> 4;
    const int bh = blockIdx.y;
    const int qt = (blockIdx.x + bh) & 31;     // balance swizzle
    const int q_base = qt * 64;
    const size_t base = (size_t)bh * S_LEN * HD;

    // ---- stage Q via global_load_lds (source-side swizzle) ----
    {
        const int c0 = (w * 2 + 0) * 64 + lane;
        const int c1 = (w * 2 + 1) * 64 + lane;
        const int r0 = c0 >> 3, k0 = (c0 & 7) ^ (r0 & 7);
        const int r1 = c1 >> 3, k1 = (c1 & 7) ^ (r1 & 7);
        g2l16(Qb + base + (size_t)(q_base + r0) * HD + k0 * 8, Qls + (w * 2 + 0) * 512);
        g2l16(Qb + base + (size_t)(q_base + r1) * HD + k1 * 8, Qls + (w * 2 + 1) * 512);
    }
    __syncthreads();

    // Q A-frags, held in regs for whole kernel (row&7 == ln&7 since w*16%8==0)
    bf16x8 aq[2];
    #pragma unroll
    for (int ks = 0; ks < 2; ++ks) {
        int row = w * 16 + ln;
        aq[ks] = *(const bf16x8*)(Qls + (row * 8 + ((ks * 4 + quad) ^ (row & 7))) * 8);
    }

    // staging pointers for K (g2l) and V (manual transpose)
    const int ck0 = (w * 2 + 0) * 64 + lane;
    const int ck1 = (w * 2 + 1) * 64 + lane;
    const int kr0 = ck0 >> 3, kk0 = (ck0 & 7) ^ (kr0 & 7);
    const int kr1 = ck1 >> 3, kk1 = (ck1 & 7) ^ (kr1 & 7);
    const u16* pK0 = Kb + base + (size_t)kr0 * HD + kk0 * 8;
    const u16* pK1 = Kb + base + (size_t)kr1 * HD + kk1 * 8;
    u16* lK0 = Kls + (w * 2 + 0) * 512;
    u16* lK1 = Kls + (w * 2 + 1) * 512;

    const int vkey0 = t >> 3,        vd0 = (t & 7) * 8;
    const int vkey1 = (t + 256) >> 3;
    const u16* pV0 = Vb + base + (size_t)vkey0 * HD + vd0;
    const u16* pV1 = Vb + base + (size_t)vkey1 * HD + vd0;

    float m_st[4], l_st[4], alpha[4];
    f32x4 o[4] = {};
    #pragma unroll
    for (int r = 0; r < 4; ++r) { m_st[r] = -1e30f; l_st[r] = 0.f; }

    const float sc = 0.125f * 1.44269504f;   // 1/sqrt(HD) * log2(e)
    const int qrow_base = q_base + w * 16;

    for (int kt = 0; kt <= qt; ++kt) {
        __syncthreads();   // prior iteration's Kls/Vt reads complete
        // ---- stage K ----
        g2l16(pK0 + (size_t)kt * 64 * HD, lK0);
        g2l16(pK1 + (size_t)kt * 64 * HD, lK1);
        // ---- stage V transposed (lane-rotated scalar writes) ----
        {
            uint4 vv0 = *(const uint4*)(pV0 + (size_t)kt * 64 * HD);
            uint4 vv1 = *(const uint4*)(pV1 + (size_t)kt * 64 * HD);
            u16 ve[8];
            *(uint4*)ve = vv0;
            int kvq = vkey0 >> 3, kvl = vkey0 & 7;
            #pragma unroll
            for (int ii = 0; ii < 8; ++ii) {
                int i = (ii + (t & 7)) & 7;
                int d = vd0 + i;
                Vt[(d * 8 + (kvq ^ (d & 7))) * 8 + kvl] = ve[i];
            }
            *(uint4*)ve = vv1;
            kvq = vkey1 >> 3; kvl = vkey1 & 7;
            #pragma unroll
            for (int ii = 0; ii < 8; ++ii) {
                int i = (ii + (t & 7)) & 7;
                int d = vd0 + i;
                Vt[(d * 8 + (kvq ^ (d & 7))) * 8 + kvl] = ve[i];
            }
        }
        __syncthreads();   // drains g2l vmcnt + manual writes

        // ---- S = Q K^T ----
        f32x4 s[4] = {};
        #pragma unroll
        for (int ks = 0; ks < 2; ++ks)
            #pragma unroll
            for (int j = 0; j < 4; ++j) {
                int krow = j * 16 + ln;
                bf16x8 bk8 = *(const bf16x8*)(Kls + (krow * 8 + ((ks * 4 + quad) ^ (krow & 7))) * 8);
                s[j] = __builtin_amdgcn_mfma_f32_16x16x32_bf16(aq[ks], bk8, s[j], 0, 0, 0);
            }

        // ---- scale (exp2 domain) + causal mask (diag tile only) ----
        if (kt == qt) {
            #pragma unroll
            for (int j = 0; j < 4; ++j)
                #pragma unroll
                for (int r = 0; r < 4; ++r) {
                    int qg = qrow_base + quad * 4 + r;
                    int kg = kt * 64 + j * 16 + ln;
                    s[j][r] = (kg > qg) ? -1e30f : s[j][r] * sc;
                }
        } else {
            #pragma unroll
            for (int j = 0; j < 4; ++j)
                #pragma unroll
                for (int r = 0; r < 4; ++r)
                    s[j][r] *= sc;
        }

        // ---- online softmax (4 rows/lane, exp2) ----
        #pragma unroll
        for (int r = 0; r < 4; ++r) {
            float mx = fmaxf(fmaxf(s[0][r], s[1][r]), fmaxf(s[2][r], s[3][r]));
            mx = qmax16(mx);
            float mnew = fmaxf(m_st[r], mx);
            float al = __builtin_amdgcn_exp2f(m_st[r] - mnew);
            m_st[r] = mnew;
            float rs = 0.f;
            #pragma unroll
            for (int j = 0; j < 4; ++j) {
                float p = __builtin_amdgcn_exp2f(s[j][r] - mnew);
                s[j][r] = p;
                rs += p;
            }
            rs = qsum16(rs);
            l_st[r] = l_st[r] * al + rs;
            alpha[r] = al;
        }
        #pragma unroll
        for (int j = 0; j < 4; ++j)
            #pragma unroll
            for (int r = 0; r < 4; ++r)
                o[j][r] *= alpha[r];

        // ---- P (C-layout) -> wave-private Ps slab (no barrier needed) ----
        #pragma unroll
        for (int j = 0; j < 4; ++j) {
            int key = j * 16 + ln;
            int kq = key >> 3, kl = key & 7;
            #pragma unroll
            for (int r = 0; r < 4; ++r) {
                int qrow = w * 16 + quad * 4 + r;
                Ps[(qrow * 8 + (kq ^ (qrow & 7))) * 8 + kl] = f2bf(s[j][r]);
            }
        }

        // ---- O += P @ V ----
        #pragma unroll
        for (int ks = 0; ks < 2; ++ks) {
            int kqg = ks * 4 + quad;
            int prow = w * 16 + ln;
            bf16x8 pa = *(const bf16x8*)(Ps + (prow * 8 + (kqg ^ (prow & 7))) * 8);
            #pragma unroll
            for (int j = 0; j < 4; ++j) {
                int rowd = j * 16 + ln;
                bf16x8 vb8 = *(const bf16x8*)(Vt + (rowd * 8 + (kqg ^ (rowd & 7))) * 8);
                o[j] = __builtin_amdgcn_mfma_f32_16x16x32_bf16(pa, vb8, o[j], 0, 0, 0);
            }
        }
    }

    // ---- epilogue: normalize, write attended bf16 [B*S, DM] ----
    const int bb = bh >> 3, h = bh & 7;
    #pragma unroll
    for (int r = 0; r < 4; ++r) {
        int qg = q_base + w * 16 + quad * 4 + r;
        float inv = 1.f / l_st[r];
        #pragma unroll
        for (int j = 0; j < 4; ++j) {
            int d = j * 16 + ln;
            Attb[((size_t)(bb * S_LEN + qg)) * DM + h * HD + d] = f2bf(o[j][r] * inv);
        }
    }
}

// ============================================================
// Output projection: out = A @ Wo^T + bo (fp32 out), m97-style staging.
// ============================================================
__global__ __launch_bounds__(256) void out_gemm(
    const u16* __restrict__ Ab, const u16* __restrict__ Wob,
    const float* __restrict__ bo, float* __restrict__ out)
{
    __shared__ u16 Als[4096];
    __shared__ u16 Bls[4096];

    const int t = threadIdx.x;
    const int lane = t & 63, w = t >> 6;
    const int ln = lane & 15, quad = lane >> 4;
    const int wm = w >> 1, wn = w & 1;
    const int m0 = blockIdx.x * 128;
    const int n0 = blockIdx.y * 128;

    const int ch0 = (w * 2 + 0) * 64 + lane;
    const int ch1 = (w * 2 + 1) * 64 + lane;
    const int sr0 = ch0 >> 2, sk0 = (ch0 & 3) ^ ((sr0 >> 1) & 3);
    const int sr1 = ch1 >> 2, sk1 = (ch1 & 3) ^ ((sr1 >> 1) & 3);
    const u16* pA0 = Ab  + (size_t)(m0 + sr0) * DM + sk0 * 8;
    const u16* pA1 = Ab  + (size_t)(m0 + sr1) * DM + sk1 * 8;
    const u16* pB0 = Wob + (size_t)(n0 + sr0) * DM + sk0 * 8;
    const u16* pB1 = Wob + (size_t)(n0 + sr1) * DM + sk1 * 8;
    u16* lA0 = Als + (w * 2 + 0) * 512;
    u16* lA1 = Als + (w * 2 + 1) * 512;
    u16* lB0 = Bls + (w * 2 + 0) * 512;
    u16* lB1 = Bls + (w * 2 + 1) * 512;

    f32x4 acc[4][4] = {};
    for (int k0 = 0; k0 < DM; k0 += 32) {
        __syncthreads();
        g2l16(pA0 + k0, lA0);
        g2l16(pA1 + k0, lA1);
        g2l16(pB0 + k0, lB0);
        g2l16(pB1 + k0, lB1);
        __syncthreads();
        bf16x8 af[4], bf8[4];
        #pragma unroll
        for (int i = 0; i < 4; ++i) {
            int row = wm * 64 + i * 16 + ln;
            af[i] = *(const bf16x8*)(Als + (row * 4 + (quad ^ ((row >> 1) & 3))) * 8);
        }
        #pragma unroll
        for (int j = 0; j < 4; ++j) {
            int row = wn * 64 + j * 16 + ln;
            bf8[j] = *(const bf16x8*)(Bls + (row * 4 + (quad ^ ((row >> 1) & 3))) * 8);
        }
        #pragma unroll
        for (int i = 0; i < 4; ++i)
            #pragma unroll
            for (int j = 0; j < 4; ++j)
                acc[i][j] = __builtin_amdgcn_mfma_f32_16x16x32_bf16(af[i], bf8[j], acc[i][j], 0, 0, 0);
    }

    #pragma unroll
    for (int j = 0; j < 4; ++j) {
        int colg = n0 + wn * 64 + j * 16 + ln;
        float bj = bo[colg];
        #pragma unroll
        for (int i = 0; i < 4; ++i) {
            int mbase = m0 + wm * 64 + i * 16 + quad * 4;
            #pragma unroll
            for (int r = 0; r < 4; ++r) {
                int m = mbase + r;
                out[(size_t)m * DM + colg] = acc[i][j][r] + bj;
            }
        }
    }
}

extern "C" void kernel_launch(void* const* d_in, const int* in_sizes, int n_in,
                              void* d_out, int out_size, void* d_ws, size_t ws_size,
                              hipStream_t stream) {
    const float* x  = (const float*)d_in[0];
    // d_in[1] = mask: exactly causal, handled analytically — unused.
    const float* Wq = (const float*)d_in[2];
    const float* bq = (const float*)d_in[3];
    const float* Wk = (const float*)d_in[4];
    const float* bk = (const float*)d_in[5];
    const float* Wv = (const float*)d_in[6];
    const float* bv = (const float*)d_in[7];
    const float* Wo = (const float*)d_in[8];
    const float* bo = (const float*)d_in[9];
    float* out = (float*)d_out;

    u16* ws = (u16*)d_ws;
    const size_t NX = (size_t)4 * S_LEN * DM;   // 4194304
    const size_t NW = (size_t)DM * DM;          // 262144
    u16* xb   = ws;
    u16* wqb  = xb + NX;
    u16* wkb  = wqb + NW;
    u16* wvb  = wkb + NW;
    u16* wob  = wvb + NW;
    u16* Qb   = wob + NW;
    u16* Kb   = Qb + NX;
    u16* Vb   = Kb + NX;
    u16* Attb = Vb + NX;

    cvt_bf16<<<dim3(2048, 5), 256, 0, stream>>>(x, Wq, Wk, Wv, Wo, xb, wqb, wkb, wvb, wob);
    qkv_gemm<<<dim3(64, 12), 256, 0, stream>>>(xb, wqb, wkb, wvb, bq, bk, bv, Qb, Kb, Vb);
    attn_mfma<<<dim3(32, 32), 256, 0, stream>>>(Qb, Kb, Vb, Attb);
    out_gemm<<<dim3(64, 4), 256, 0, stream>>>(Attb, wob, bo, out);
}

// Round 4
// 749.358 us; speedup vs baseline: 1.0361x; 1.0361x over previous
//
#include <hip/hip_runtime.h>

#define S_LEN 2048
#define DM    512
#define NH    8
#define HD    64

typedef unsigned short u16;
typedef unsigned int   u32;
typedef __bf16 bf16_t;
typedef bf16_t bf16x8 __attribute__((ext_vector_type(8)));
typedef float  f32x4  __attribute__((ext_vector_type(4)));

// round-to-nearest-even fp32 -> bf16
__device__ __forceinline__ u16 f2bf(float f) {
    u32 u = __float_as_uint(f);
    u += 0x7FFFu + ((u >> 16) & 1u);
    return (u16)(u >> 16);
}

// async global->LDS, 16B per lane; LDS dest = wave-uniform base + lane*16
__device__ __forceinline__ void g2l16(const u16* g, u16* l) {
    __builtin_amdgcn_global_load_lds(
        (const __attribute__((address_space(1))) u32*)g,
        (__attribute__((address_space(3))) u32*)l,
        16, 0, 0);
}

__device__ __forceinline__ float qmax16(float v) {
    v = fmaxf(v, __shfl_xor(v, 1));
    v = fmaxf(v, __shfl_xor(v, 2));
    v = fmaxf(v, __shfl_xor(v, 4));
    v = fmaxf(v, __shfl_xor(v, 8));
    return v;
}
__device__ __forceinline__ float qsum16(float v) {
    v += __shfl_xor(v, 1);
    v += __shfl_xor(v, 2);
    v += __shfl_xor(v, 4);
    v += __shfl_xor(v, 8);
    return v;
}

// ============================================================
// fp32 -> bf16 conversion pre-pass. y selects source.
// ============================================================
__global__ __launch_bounds__(256) void cvt_bf16(
    const float* __restrict__ x,
    const float* __restrict__ wq, const float* __restrict__ wk,
    const float* __restrict__ wv, const float* __restrict__ wo,
    u16* __restrict__ xb, u16* __restrict__ wqb, u16* __restrict__ wkb,
    u16* __restrict__ wvb, u16* __restrict__ wob)
{
    const int y = blockIdx.y;
    const float* src; u16* dst; int n;
    if (y == 0)      { src = x;  dst = xb;  n = 4 * S_LEN * DM; }
    else if (y == 1) { src = wq; dst = wqb; n = DM * DM; }
    else if (y == 2) { src = wk; dst = wkb; n = DM * DM; }
    else if (y == 3) { src = wv; dst = wvb; n = DM * DM; }
    else             { src = wo; dst = wob; n = DM * DM; }
    int idx = (blockIdx.x * 256 + threadIdx.x) * 8;
    if (idx >= n) return;
    float4 f0 = *(const float4*)(src + idx);
    float4 f1 = *(const float4*)(src + idx + 4);
    u32 p0 = (u32)f2bf(f0.x) | ((u32)f2bf(f0.y) << 16);
    u32 p1 = (u32)f2bf(f0.z) | ((u32)f2bf(f0.w) << 16);
    u32 p2 = (u32)f2bf(f1.x) | ((u32)f2bf(f1.y) << 16);
    u32 p3 = (u32)f2bf(f1.z) | ((u32)f2bf(f1.w) << 16);
    *(uint4*)(dst + idx) = make_uint4(p0, p1, p2, p3);
}

// ============================================================
// Fused QKV MFMA GEMM: C = X @ W^T + b, 128x128 tile, BK=32.
// Double-buffered g2l staging: prefetch for iter it+1 issued AFTER the
// barrier of iter it, so the vmcnt drain at the NEXT barrier lands after a
// full compute phase (latency hidden). Source-side XOR swizzle as before.
// ============================================================
__global__ __launch_bounds__(256) void qkv_gemm(
    const u16* __restrict__ xb,
    const u16* __restrict__ Wqb, const u16* __restrict__ Wkb, const u16* __restrict__ Wvb,
    const float* __restrict__ bq, const float* __restrict__ bk, const float* __restrict__ bv,
    u16* __restrict__ Qb, u16* __restrict__ Kb, u16* __restrict__ Vb)
{
    __shared__ u16 Als[2][4096];
    __shared__ u16 Bls[2][4096];

    const int t = threadIdx.x;
    const int lane = t & 63, w = t >> 6;
    const int ln = lane & 15, quad = lane >> 4;
    const int wm = w >> 1, wn = w & 1;
    const int m0 = blockIdx.x * 128;
    const int mat = blockIdx.y >> 2;          // 0=Q 1=K 2=V
    const int n0 = (blockIdx.y & 3) * 128;

    const u16* __restrict__ Wb     = (mat == 0) ? Wqb : (mat == 1) ? Wkb : Wvb;
    const float* __restrict__ bias = (mat == 0) ? bq : (mat == 1) ? bk : bv;
    u16* __restrict__ outp         = (mat == 0) ? Qb : (mat == 1) ? Kb : Vb;

    const int ch0 = (w * 2 + 0) * 64 + lane;
    const int ch1 = (w * 2 + 1) * 64 + lane;
    const int sr0 = ch0 >> 2, sk0 = (ch0 & 3) ^ ((sr0 >> 1) & 3);
    const int sr1 = ch1 >> 2, sk1 = (ch1 & 3) ^ ((sr1 >> 1) & 3);
    const u16* pA0 = xb + (size_t)(m0 + sr0) * DM + sk0 * 8;
    const u16* pA1 = xb + (size_t)(m0 + sr1) * DM + sk1 * 8;
    const u16* pB0 = Wb + (size_t)(n0 + sr0) * DM + sk0 * 8;
    const u16* pB1 = Wb + (size_t)(n0 + sr1) * DM + sk1 * 8;
    const int lo0 = (w * 2 + 0) * 512;
    const int lo1 = (w * 2 + 1) * 512;

    // prologue: stage k0=0 into buffer 0 (drained by barrier at it=0)
    g2l16(pA0, &Als[0][lo0]);
    g2l16(pA1, &Als[0][lo1]);
    g2l16(pB0, &Bls[0][lo0]);
    g2l16(pB1, &Bls[0][lo1]);

    f32x4 acc[4][4] = {};
    for (int it = 0; it < 16; ++it) {
        const int cur = it & 1, nxt = cur ^ 1;
        __syncthreads();   // drains buf[cur] g2l; releases buf[nxt] for staging
        if (it + 1 < 16) {
            const int k0n = (it + 1) * 32;
            g2l16(pA0 + k0n, &Als[nxt][lo0]);
            g2l16(pA1 + k0n, &Als[nxt][lo1]);
            g2l16(pB0 + k0n, &Bls[nxt][lo0]);
            g2l16(pB1 + k0n, &Bls[nxt][lo1]);
        }
        bf16x8 af[4], bf8[4];
        #pragma unroll
        for (int i = 0; i < 4; ++i) {
            int row = wm * 64 + i * 16 + ln;
            af[i] = *(const bf16x8*)(&Als[cur][0] + (row * 4 + (quad ^ ((row >> 1) & 3))) * 8);
        }
        #pragma unroll
        for (int j = 0; j < 4; ++j) {
            int row = wn * 64 + j * 16 + ln;
            bf8[j] = *(const bf16x8*)(&Bls[cur][0] + (row * 4 + (quad ^ ((row >> 1) & 3))) * 8);
        }
        #pragma unroll
        for (int i = 0; i < 4; ++i)
            #pragma unroll
            for (int j = 0; j < 4; ++j)
                acc[i][j] = __builtin_amdgcn_mfma_f32_16x16x32_bf16(af[i], bf8[j], acc[i][j], 0, 0, 0);
    }

    // epilogue: C/D layout col=lane&15, row=quad*4+reg  [m89/m91]
    #pragma unroll
    for (int j = 0; j < 4; ++j) {
        int colg = n0 + wn * 64 + j * 16 + ln;
        float bj = bias[colg];
        int h = colg >> 6, d = colg & 63;
        #pragma unroll
        for (int i = 0; i < 4; ++i) {
            int mbase = m0 + wm * 64 + i * 16 + quad * 4;
            #pragma unroll
            for (int r = 0; r < 4; ++r) {
                int m = mbase + r;
                int bb = m >> 11, s = m & 2047;
                outp[(((size_t)bb * NH + h) * S_LEN + s) * HD + d] = f2bf(acc[i][j][r] + bj);
            }
        }
    }
}

// ============================================================
// Flash attention, bf16 MFMA, causal. grid = (32, B*H).
// Block: 64 q-rows, 4 waves x 16 rows. Double-buffered K (g2l) and
// V-transpose (regs->LDS) staging, ONE barrier per K-iteration:
//   barrier -> prefetch(kt+1) -> QK(cur) -> write Vt[nxt] -> softmax -> PV(cur)
// 48 KB LDS -> 3 blocks/CU. qt swizzled (x+y)&31 for balance.
// ============================================================
__global__ __launch_bounds__(256) void attn_mfma(
    const u16* __restrict__ Qb, const u16* __restrict__ Kb, const u16* __restrict__ Vb,
    u16* __restrict__ Attb)
{
    __shared__ u16 Qls[4096];       // 64 q x 64 d
    __shared__ u16 Kls[2][4096];    // 64 k x 64 d, double-buffered
    __shared__ u16 Vt[2][4096];     // 64 d x 64 k (transposed), double-buffered
    __shared__ u16 Ps[4096];        // 64 q x 64 k, wave-private slabs

    const int t = threadIdx.x;
    const int lane = t & 63, w = t >> 6;
    const int ln = lane & 15, quad = lane >> 4;
    const int bh = blockIdx.y;
    const int qt = (blockIdx.x + bh) & 31;     // balance swizzle
    const int q_base = qt * 64;
    const size_t base = (size_t)bh * S_LEN * HD;

    // staging geometry (shared by Q and K)
    const int c0 = (w * 2 + 0) * 64 + lane;
    const int c1 = (w * 2 + 1) * 64 + lane;
    const int r0 = c0 >> 3, k0s = (c0 & 7) ^ (r0 & 7);
    const int r1 = c1 >> 3, k1s = (c1 & 7) ^ (r1 & 7);
    const int lo0 = (w * 2 + 0) * 512;
    const int lo1 = (w * 2 + 1) * 512;

    // ---- prologue: stage Q, prefetch K/V for kt=0 ----
    g2l16(Qb + base + (size_t)(q_base + r0) * HD + k0s * 8, Qls + lo0);
    g2l16(Qb + base + (size_t)(q_base + r1) * HD + k1s * 8, Qls + lo1);

    const u16* pK0 = Kb + base + (size_t)r0 * HD + k0s * 8;
    const u16* pK1 = Kb + base + (size_t)r1 * HD + k1s * 8;
    g2l16(pK0, &Kls[0][lo0]);
    g2l16(pK1, &Kls[0][lo1]);

    const int vkey0 = t >> 3, vd0 = (t & 7) * 8;
    const int vkey1 = (t + 256) >> 3;
    const u16* pV0 = Vb + base + (size_t)vkey0 * HD + vd0;
    const u16* pV1 = Vb + base + (size_t)vkey1 * HD + vd0;
    const int kvq0 = vkey0 >> 3, kvl0 = vkey0 & 7;
    const int kvq1 = vkey1 >> 3, kvl1 = vkey1 & 7;

    {   // V(kt=0) -> Vt[0]
        uint4 vv0 = *(const uint4*)(pV0);
        uint4 vv1 = *(const uint4*)(pV1);
        u16 ve[8];
        *(uint4*)ve = vv0;
        #pragma unroll
        for (int ii = 0; ii < 8; ++ii) {
            int i = (ii + (t & 7)) & 7;
            int d = vd0 + i;
            Vt[0][(d * 8 + (kvq0 ^ (d & 7))) * 8 + kvl0] = ve[i];
        }
        *(uint4*)ve = vv1;
        #pragma unroll
        for (int ii = 0; ii < 8; ++ii) {
            int i = (ii + (t & 7)) & 7;
            int d = vd0 + i;
            Vt[0][(d * 8 + (kvq1 ^ (d & 7))) * 8 + kvl1] = ve[i];
        }
    }
    __syncthreads();   // Q + Kls[0] g2l drained; Vt[0] visible

    // Q A-frags, held in regs for whole kernel
    bf16x8 aq[2];
    #pragma unroll
    for (int ks = 0; ks < 2; ++ks) {
        int row = w * 16 + ln;
        aq[ks] = *(const bf16x8*)(Qls + (row * 8 + ((ks * 4 + quad) ^ (row & 7))) * 8);
    }

    float m_st[4], l_st[4], alpha[4];
    f32x4 o[4] = {};
    #pragma unroll
    for (int r = 0; r < 4; ++r) { m_st[r] = -1e30f; l_st[r] = 0.f; }

    const float sc = 0.125f * 1.44269504f;   // 1/sqrt(HD) * log2(e)
    const int qrow_base = q_base + w * 16;

    for (int kt = 0; kt <= qt; ++kt) {
        const int cur = kt & 1, nxt = cur ^ 1;
        __syncthreads();   // buf[cur] staged+visible; buf[nxt] free

        // ---- prefetch kt+1 (K async to LDS, V to regs) ----
        uint4 vv0, vv1;
        const bool more = (kt < qt);
        if (more) {
            const size_t off = (size_t)(kt + 1) * 64 * HD;
            g2l16(pK0 + off, &Kls[nxt][lo0]);
            g2l16(pK1 + off, &Kls[nxt][lo1]);
            vv0 = *(const uint4*)(pV0 + off);
            vv1 = *(const uint4*)(pV1 + off);
        }

        // ---- S = Q K^T on buf[cur] ----
        f32x4 s[4] = {};
        #pragma unroll
        for (int ks = 0; ks < 2; ++ks)
            #pragma unroll
            for (int j = 0; j < 4; ++j) {
                int krow = j * 16 + ln;
                bf16x8 bk8 = *(const bf16x8*)(&Kls[cur][0] + (krow * 8 + ((ks * 4 + quad) ^ (krow & 7))) * 8);
                s[j] = __builtin_amdgcn_mfma_f32_16x16x32_bf16(aq[ks], bk8, s[j], 0, 0, 0);
            }

        // ---- write V(kt+1) -> Vt[nxt] (readers passed this iter's barrier) ----
        if (more) {
            u16 ve[8];
            *(uint4*)ve = vv0;
            #pragma unroll
            for (int ii = 0; ii < 8; ++ii) {
                int i = (ii + (t & 7)) & 7;
                int d = vd0 + i;
                Vt[nxt][(d * 8 + (kvq0 ^ (d & 7))) * 8 + kvl0] = ve[i];
            }
            *(uint4*)ve = vv1;
            #pragma unroll
            for (int ii = 0; ii < 8; ++ii) {
                int i = (ii + (t & 7)) & 7;
                int d = vd0 + i;
                Vt[nxt][(d * 8 + (kvq1 ^ (d & 7))) * 8 + kvl1] = ve[i];
            }
        }

        // ---- scale (exp2 domain) + causal mask (diag tile only) ----
        if (kt == qt) {
            #pragma unroll
            for (int j = 0; j < 4; ++j)
                #pragma unroll
                for (int r = 0; r < 4; ++r) {
                    int qg = qrow_base + quad * 4 + r;
                    int kg = kt * 64 + j * 16 + ln;
                    s[j][r] = (kg > qg) ? -1e30f : s[j][r] * sc;
                }
        } else {
            #pragma unroll
            for (int j = 0; j < 4; ++j)
                #pragma unroll
                for (int r = 0; r < 4; ++r)
                    s[j][r] *= sc;
        }

        // ---- online softmax (4 rows/lane, exp2) ----
        #pragma unroll
        for (int r = 0; r < 4; ++r) {
            float mx = fmaxf(fmaxf(s[0][r], s[1][r]), fmaxf(s[2][r], s[3][r]));
            mx = qmax16(mx);
            float mnew = fmaxf(m_st[r], mx);
            float al = __builtin_amdgcn_exp2f(m_st[r] - mnew);
            m_st[r] = mnew;
            float rs = 0.f;
            #pragma unroll
            for (int j = 0; j < 4; ++j) {
                float p = __builtin_amdgcn_exp2f(s[j][r] - mnew);
                s[j][r] = p;
                rs += p;
            }
            rs = qsum16(rs);
            l_st[r] = l_st[r] * al + rs;
            alpha[r] = al;
        }
        #pragma unroll
        for (int j = 0; j < 4; ++j)
            #pragma unroll
            for (int r = 0; r < 4; ++r)
                o[j][r] *= alpha[r];

        // ---- P (C-layout) -> wave-private Ps slab ----
        #pragma unroll
        for (int j = 0; j < 4; ++j) {
            int key = j * 16 + ln;
            int kq = key >> 3, kl = key & 7;
            #pragma unroll
            for (int r = 0; r < 4; ++r) {
                int qrow = w * 16 + quad * 4 + r;
                Ps[(qrow * 8 + (kq ^ (qrow & 7))) * 8 + kl] = f2bf(s[j][r]);
            }
        }

        // ---- O += P @ V on buf[cur] ----
        #pragma unroll
        for (int ks = 0; ks < 2; ++ks) {
            int kqg = ks * 4 + quad;
            int prow = w * 16 + ln;
            bf16x8 pa = *(const bf16x8*)(Ps + (prow * 8 + (kqg ^ (prow & 7))) * 8);
            #pragma unroll
            for (int j = 0; j < 4; ++j) {
                int rowd = j * 16 + ln;
                bf16x8 vb8 = *(const bf16x8*)(&Vt[cur][0] + (rowd * 8 + (kqg ^ (rowd & 7))) * 8);
                o[j] = __builtin_amdgcn_mfma_f32_16x16x32_bf16(pa, vb8, o[j], 0, 0, 0);
            }
        }
    }

    // ---- epilogue: normalize, write attended bf16 [B*S, DM] ----
    const int bb = bh >> 3, h = bh & 7;
    #pragma unroll
    for (int r = 0; r < 4; ++r) {
        int qg = q_base + w * 16 + quad * 4 + r;
        float inv = 1.f / l_st[r];
        #pragma unroll
        for (int j = 0; j < 4; ++j) {
            int d = j * 16 + ln;
            Attb[((size_t)(bb * S_LEN + qg)) * DM + h * HD + d] = f2bf(o[j][r] * inv);
        }
    }
}

// ============================================================
// Output projection: out = A @ Wo^T + bo (fp32 out), dbuf staging.
// ============================================================
__global__ __launch_bounds__(256) void out_gemm(
    const u16* __restrict__ Ab, const u16* __restrict__ Wob,
    const float* __restrict__ bo, float* __restrict__ out)
{
    __shared__ u16 Als[2][4096];
    __shared__ u16 Bls[2][4096];

    const int t = threadIdx.x;
    const int lane = t & 63, w = t >> 6;
    const int ln = lane & 15, quad = lane >> 4;
    const int wm = w >> 1, wn = w & 1;
    const int m0 = blockIdx.x * 128;
    const int n0 = blockIdx.y * 128;

    const int ch0 = (w * 2 + 0) * 64 + lane;
    const int ch1 = (w * 2 + 1) * 64 + lane;
    const int sr0 = ch0 >> 2, sk0 = (ch0 & 3) ^ ((sr0 >> 1) & 3);
    const int sr1 = ch1 >> 2, sk1 = (ch1 & 3) ^ ((sr1 >> 1) & 3);
    const u16* pA0 = Ab  + (size_t)(m0 + sr0) * DM + sk0 * 8;
    const u16* pA1 = Ab  + (size_t)(m0 + sr1) * DM + sk1 * 8;
    const u16* pB0 = Wob + (size_t)(n0 + sr0) * DM + sk0 * 8;
    const u16* pB1 = Wob + (size_t)(n0 + sr1) * DM + sk1 * 8;
    const int lo0 = (w * 2 + 0) * 512;
    const int lo1 = (w * 2 + 1) * 512;

    g2l16(pA0, &Als[0][lo0]);
    g2l16(pA1, &Als[0][lo1]);
    g2l16(pB0, &Bls[0][lo0]);
    g2l16(pB1, &Bls[0][lo1]);

    f32x4 acc[4][4] = {};
    for (int it = 0; it < 16; ++it) {
        const int cur = it & 1, nxt = cur ^ 1;
        __syncthreads();
        if (it + 1 < 16) {
            const int k0n = (it + 1) * 32;
            g2l16(pA0 + k0n, &Als[nxt][lo0]);
            g2l16(pA1 + k0n, &Als[nxt][lo1]);
            g2l16(pB0 + k0n, &Bls[nxt][lo0]);
            g2l16(pB1 + k0n, &Bls[nxt][lo1]);
        }
        bf16x8 af[4], bf8[4];
        #pragma unroll
        for (int i = 0; i < 4; ++i) {
            int row = wm * 64 + i * 16 + ln;
            af[i] = *(const bf16x8*)(&Als[cur][0] + (row * 4 + (quad ^ ((row >> 1) & 3))) * 8);
        }
        #pragma unroll
        for (int j = 0; j < 4; ++j) {
            int row = wn * 64 + j * 16 + ln;
            bf8[j] = *(const bf16x8*)(&Bls[cur][0] + (row * 4 + (quad ^ ((row >> 1) & 3))) * 8);
        }
        #pragma unroll
        for (int i = 0; i < 4; ++i)
            #pragma unroll
            for (int j = 0; j < 4; ++j)
                acc[i][j] = __builtin_amdgcn_mfma_f32_16x16x32_bf16(af[i], bf8[j], acc[i][j], 0, 0, 0);
    }

    #pragma unroll
    for (int j = 0; j < 4; ++j) {
        int colg = n0 + wn * 64 + j * 16 + ln;
        float bj = bo[colg];
        #pragma unroll
        for (int i = 0; i < 4; ++i) {
            int mbase = m0 + wm * 64 + i * 16 + quad * 4;
            #pragma unroll
            for (int r = 0; r < 4; ++r) {
                int m = mbase + r;
                out[(size_t)m * DM + colg] = acc[i][j][r] + bj;
            }
        }
    }
}

extern "C" void kernel_launch(void* const* d_in, const int* in_sizes, int n_in,
                              void* d_out, int out_size, void* d_ws, size_t ws_size,
                              hipStream_t stream) {
    const float* x  = (const float*)d_in[0];
    // d_in[1] = mask: exactly causal, handled analytically — unused.
    const float* Wq = (const float*)d_in[2];
    const float* bq = (const float*)d_in[3];
    const float* Wk = (const float*)d_in[4];
    const float* bk = (const float*)d_in[5];
    const float* Wv = (const float*)d_in[6];
    const float* bv = (const float*)d_in[7];
    const float* Wo = (const float*)d_in[8];
    const float* bo = (const float*)d_in[9];
    float* out = (float*)d_out;

    u16* ws = (u16*)d_ws;
    const size_t NX = (size_t)4 * S_LEN * DM;   // 4194304
    const size_t NW = (size_t)DM * DM;          // 262144
    u16* xb   = ws;
    u16* wqb  = xb + NX;
    u16* wkb  = wqb + NW;
    u16* wvb  = wkb + NW;
    u16* wob  = wvb + NW;
    u16* Qb   = wob + NW;
    u16* Kb   = Qb + NX;
    u16* Vb   = Kb + NX;
    u16* Attb = Vb + NX;

    cvt_bf16<<<dim3(2048, 5), 256, 0, stream>>>(x, Wq, Wk, Wv, Wo, xb, wqb, wkb, wvb, wob);
    qkv_gemm<<<dim3(64, 12), 256, 0, stream>>>(xb, wqb, wkb, wvb, bq, bk, bv, Qb, Kb, Vb);
    attn_mfma<<<dim3(32, 32), 256, 0, stream>>>(Qb, Kb, Vb, Attb);
    out_gemm<<<dim3(64, 4), 256, 0, stream>>>(Attb, wob, bo, out);
}